// Round 1
// baseline (1305.289 us; speedup 1.0000x reference)
//
#include <hip/hip_runtime.h>
#include <hip/hip_bf16.h>
#include <stdint.h>

#define B_TOK 65536
#define DM 1024
#define NC 1024
#define NT 16

typedef __attribute__((ext_vector_type(4))) float f32x4;
typedef __attribute__((ext_vector_type(4))) unsigned int u32x4;
typedef __attribute__((ext_vector_type(4))) unsigned short u16x4;
typedef __attribute__((ext_vector_type(8))) short short8;

#define AS1(p) ((__attribute__((address_space(1))) void*)(p))
#define AS3(p) ((__attribute__((address_space(3))) void*)(p))

static __device__ inline unsigned short f2bf(float f) {
  __hip_bfloat16 h = __float2bfloat16(f);
  unsigned short u;
  __builtin_memcpy(&u, &h, 2);
  return u;
}

// ---- build ternary masks: bit t = pos (s>0.3), bit 16+t = neg (s<-0.3) ----
__global__ void k_masks(const float* __restrict__ sigs, unsigned int* __restrict__ mask) {
  int d = threadIdx.x;
  unsigned int m = 0;
#pragma unroll
  for (int t = 0; t < NT; ++t) {
    float s = sigs[t * DM + d];
    if (s > 0.3f) m |= 1u << t;
    else if (s < -0.3f) m |= 1u << (16 + t);
  }
  mask[d] = m;
}

// ---- scores (f64 accum) + argmax + x->bf16 convert + counts ----
__global__ __launch_bounds__(256) void k_scores(const float* __restrict__ x,
    const unsigned int* __restrict__ mask, unsigned short* __restrict__ xb,
    int* __restrict__ tidx, float* __restrict__ oidx, int* __restrict__ counts)
{
  int tid = threadIdx.x;
  int l = tid & 63;
  int gw = (blockIdx.x * 256 + tid) >> 6;  // global wave id, 0..4095
  const u32x4* M4 = (const u32x4*)mask;
  u32x4 m4[4];
#pragma unroll
  for (int q = 0; q < 4; ++q) m4[q] = M4[q * 64 + l];
  const f32x4* X4 = (const f32x4*)x;
  u16x4* XB4 = (u16x4*)xb;

  for (int tok = gw; tok < B_TOK; tok += 4096) {
    double acc[NT];
#pragma unroll
    for (int t = 0; t < NT; ++t) acc[t] = 0.0;
#pragma unroll
    for (int q = 0; q < 4; ++q) {
      f32x4 xv = X4[tok * 256 + q * 64 + l];
      u16x4 o;
#pragma unroll
      for (int j = 0; j < 4; ++j) o[j] = f2bf(xv[j]);
      XB4[tok * 256 + q * 64 + l] = o;
#pragma unroll
      for (int j = 0; j < 4; ++j) {
        double xd = (double)xv[j];
        double xnd = -xd;
        unsigned int w = m4[q][j];
#pragma unroll
        for (int t = 0; t < NT; ++t) {
          double a = ((w >> t) & 1u) ? xd : (((w >> (16 + t)) & 1u) ? xnd : 0.0);
          acc[t] += a;
        }
      }
    }
    // wave butterfly reduce (f64, deterministic)
#pragma unroll
    for (int t = 0; t < NT; ++t) {
      double v = acc[t];
#pragma unroll
      for (int off = 32; off > 0; off >>= 1) v += __shfl_xor(v, off);
      acc[t] = v;
    }
    int best = 0;
    double bv = acc[0];
#pragma unroll
    for (int t = 1; t < NT; ++t) if (acc[t] > bv) { bv = acc[t]; best = t; }
    if (l == 0) {
      tidx[tok] = best;
      oidx[tok] = (float)best;
      atomicAdd(&counts[best], 1);
    }
  }
}

// ---- W f32 -> bf16 ----
__global__ __launch_bounds__(256) void k_wconv(const float* __restrict__ W, unsigned short* __restrict__ Wb) {
  const f32x4* W4 = (const f32x4*)W;
  u16x4* O = (u16x4*)Wb;
  int n4 = NT * NC * DM / 4;
  for (int i = blockIdx.x * blockDim.x + threadIdx.x; i < n4; i += gridDim.x * blockDim.x) {
    f32x4 v = W4[i];
    u16x4 o;
#pragma unroll
    for (int j = 0; j < 4; ++j) o[j] = f2bf(v[j]);
    O[i] = o;
  }
}

// ---- padded exclusive scan of counts (pad to 128) ----
__global__ void k_scan(const int* __restrict__ counts, int* __restrict__ offs) {
  if (threadIdx.x == 0) {
    int s = 0;
    for (int t = 0; t < NT; ++t) {
      offs[t] = s;
      s += (counts[t] + 127) & ~127;
    }
    offs[NT] = s;
  }
}

// ---- scatter tokens into per-tile segments ----
__global__ __launch_bounds__(256) void k_place(const int* __restrict__ tidx, const int* __restrict__ offs,
                                               int* __restrict__ cursor, int* __restrict__ perm) {
  int tok = blockIdx.x * 256 + threadIdx.x;
  if (tok >= B_TOK) return;
  int t = tidx[tok];
  int pos = atomicAdd(&cursor[t], 1);
  perm[offs[t] + pos] = tok;
}

// ---- grouped GEMM: 128x128 tile, BK=32, 4 waves, mfma 16x16x32 bf16 ----
__global__ __launch_bounds__(256) void k_gemm(const unsigned short* __restrict__ xb,
    const unsigned short* __restrict__ Wb, const float* __restrict__ bias,
    const int* __restrict__ perm, const int* __restrict__ offs, float* __restrict__ out)
{
  __shared__ unsigned short As[128 * 32];  // [row][k] 8KB
  __shared__ unsigned short Bs[128 * 32];  // [class][k] 8KB
  int bid = blockIdx.x;
  int mb = bid >> 3, nb = bid & 7;
  int total = offs[NT];
  int m0 = mb << 7;
  if (m0 >= total) return;
  int t = 0;
#pragma unroll
  for (int tt = 0; tt < NT; ++tt) if (m0 >= offs[tt + 1]) t = tt + 1;
  int c0 = nb << 7;
  int tid = threadIdx.x;

  // staging: thread covers 16B; round r covers rows r*64 + tid/4, k-chunk (tid%4)*8
  int rowA = tid >> 2;
  int kb = (tid & 3) << 3;
  int tok0 = perm[m0 + rowA];       if (tok0 < 0) tok0 = 0;
  int tok1 = perm[m0 + 64 + rowA];  if (tok1 < 0) tok1 = 0;
  const unsigned short* gA0 = xb + (size_t)tok0 * DM + kb;
  const unsigned short* gA1 = xb + (size_t)tok1 * DM + kb;
  const unsigned short* gWt = Wb + (size_t)t * NC * DM;
  const unsigned short* gB0 = gWt + (size_t)(c0 + rowA) * DM + kb;
  const unsigned short* gB1 = gWt + (size_t)(c0 + 64 + rowA) * DM + kb;

  f32x4 acc[4][4];
#pragma unroll
  for (int m = 0; m < 4; ++m)
#pragma unroll
    for (int n = 0; n < 4; ++n) acc[m][n] = (f32x4){0.f, 0.f, 0.f, 0.f};

  int w = tid >> 6, l = tid & 63;
  int wr = w >> 1, wc = w & 1;     // 2x2 waves -> 64x64 each
  int lr = l & 15, lk = l >> 4;

  for (int kk = 0; kk < DM; kk += 32) {
    __syncthreads();  // previous compute done before overwrite
    __builtin_amdgcn_global_load_lds(AS1(gA0 + kk), AS3(As + tid * 8), 16, 0, 0);
    __builtin_amdgcn_global_load_lds(AS1(gA1 + kk), AS3(As + 2048 + tid * 8), 16, 0, 0);
    __builtin_amdgcn_global_load_lds(AS1(gB0 + kk), AS3(Bs + tid * 8), 16, 0, 0);
    __builtin_amdgcn_global_load_lds(AS1(gB1 + kk), AS3(Bs + 2048 + tid * 8), 16, 0, 0);
    __syncthreads();  // drains vmcnt before ds_read

    short8 a[4], b[4];
#pragma unroll
    for (int m = 0; m < 4; ++m)
      a[m] = *(const short8*)&As[(wr * 64 + m * 16 + lr) * 32 + lk * 8];
#pragma unroll
    for (int n = 0; n < 4; ++n)
      b[n] = *(const short8*)&Bs[(wc * 64 + n * 16 + lr) * 32 + lk * 8];
#pragma unroll
    for (int m = 0; m < 4; ++m)
#pragma unroll
      for (int n = 0; n < 4; ++n)
        acc[m][n] = __builtin_amdgcn_mfma_f32_16x16x32_bf16(a[m], b[n], acc[m][n], 0, 0, 0);
  }

  // epilogue: C row = (l>>4)*4 + j, col = l&15
  float bv[4];
#pragma unroll
  for (int n = 0; n < 4; ++n) bv[n] = bias[t * NC + c0 + wc * 64 + n * 16 + lr];
#pragma unroll
  for (int m = 0; m < 4; ++m) {
#pragma unroll
    for (int j = 0; j < 4; ++j) {
      int prow = m0 + wr * 64 + m * 16 + lk * 4 + j;
      int tok = perm[prow];
      if (tok >= 0) {
#pragma unroll
        for (int n = 0; n < 4; ++n)
          out[(size_t)tok * NC + c0 + wc * 64 + n * 16 + lr] = acc[m][n][j] + bv[n];
      }
    }
  }
}

extern "C" void kernel_launch(void* const* d_in, const int* in_sizes, int n_in,
                              void* d_out, int out_size, void* d_ws, size_t ws_size,
                              hipStream_t stream) {
  const float* x    = (const float*)d_in[0];
  const float* sigs = (const float*)d_in[1];
  const float* W    = (const float*)d_in[2];
  const float* bias = (const float*)d_in[3];
  float* out = (float*)d_out;
  float* oidx = out + (size_t)B_TOK * NC;

  char* ws = (char*)d_ws;
  unsigned short* xb   = (unsigned short*)ws;                    // 134217728 B
  unsigned short* Wb   = (unsigned short*)(ws + 134217728);      // 33554432 B
  int* perm            = (int*)(ws + 167772160);                 // 270336 B (67584 rows)
  int* tidx            = (int*)(ws + 168042496);                 // 262144 B
  unsigned int* mask   = (unsigned int*)(ws + 168304640);        // 4096 B
  int* ctrl            = (int*)(ws + 168308736);                 // counts16 cursor16 offs17
  int* counts = ctrl;
  int* cursor = ctrl + 16;
  int* offs   = ctrl + 32;

  hipMemsetAsync(perm, 0xFF, 270336, stream);   // perm = -1 (pad marker)
  hipMemsetAsync(ctrl, 0, 256, stream);

  k_masks<<<1, 1024, 0, stream>>>(sigs, mask);
  k_scores<<<1024, 256, 0, stream>>>(x, mask, xb, tidx, oidx, counts);
  k_wconv<<<2048, 256, 0, stream>>>(W, Wb);
  k_scan<<<1, 64, 0, stream>>>(counts, offs);
  k_place<<<256, 256, 0, stream>>>(tidx, offs, cursor, perm);
  k_gemm<<<dim3(528 * 8), 256, 0, stream>>>(xb, Wb, bias, perm, offs, out);
}

// Round 3
// 667.631 us; speedup vs baseline: 1.9551x; 1.9551x over previous
//
#include <hip/hip_runtime.h>
#include <hip/hip_bf16.h>
#include <stdint.h>

#define B_TOK 65536
#define DM 1024
#define NC 1024
#define NT 16
#define GAPTHR 0.25f

typedef __attribute__((ext_vector_type(4))) float f32x4;
typedef __attribute__((ext_vector_type(4))) unsigned int u32x4;
typedef __attribute__((ext_vector_type(4))) unsigned short u16x4;
typedef __attribute__((ext_vector_type(8))) short short8;

#define AS1(p) ((__attribute__((address_space(1))) void*)(p))
#define AS3(p) ((__attribute__((address_space(3))) void*)(p))

static __device__ inline unsigned short f2bf(float f) {
  __hip_bfloat16 h = __float2bfloat16(f);
  unsigned short u;
  __builtin_memcpy(&u, &h, 2);
  return u;
}

// ---- prep: ternary masks (bit t = pos, bit 16+t = neg) + ternary bf16 matrix S[16][1024] ----
__global__ void k_prep(const float* __restrict__ sigs, unsigned int* __restrict__ mask,
                       unsigned short* __restrict__ Sb) {
  int d = threadIdx.x;
  unsigned int m = 0;
#pragma unroll
  for (int t = 0; t < NT; ++t) {
    float s = sigs[t * DM + d];
    float q = (s > 0.3f) ? 1.0f : ((s < -0.3f) ? -1.0f : 0.0f);
    if (s > 0.3f) m |= 1u << t;
    else if (s < -0.3f) m |= 1u << (16 + t);
    Sb[t * DM + d] = f2bf(q);   // {-1,0,1} exact in bf16
  }
  mask[d] = m;
}

// ---- provisional scores via bf16 MFMA (verified layout) + top-2 gap + x->bf16 ----
// wave handles 16 tokens: A lane l = x[tok0 + (l&15)][k=(l>>4)*8+j], B lane l = S[tile=l&15][k]
__global__ __launch_bounds__(256) void k_scores(const float* __restrict__ x,
    const unsigned short* __restrict__ Sb, unsigned short* __restrict__ xb,
    int* __restrict__ tidx, float* __restrict__ oidx,
    int* __restrict__ fixlist, int* __restrict__ nfix)
{
  int tid = threadIdx.x;
  int w = tid >> 6, l = tid & 63;
  int lr = l & 15, lg = l >> 4;
  int tok0 = blockIdx.x * 64 + w * 16;

  const float* xr = x + (size_t)(tok0 + lr) * DM + lg * 8;
  unsigned short* xbr = xb + (size_t)(tok0 + lr) * DM + lg * 8;
  const unsigned short* sr = Sb + (size_t)lr * DM + lg * 8;

  f32x4 acc = (f32x4){0.f, 0.f, 0.f, 0.f};
  for (int kc = 0; kc < 32; ++kc) {
    f32x4 v0 = *(const f32x4*)(xr + kc * 32);
    f32x4 v1 = *(const f32x4*)(xr + kc * 32 + 4);
    short8 a;
#pragma unroll
    for (int j = 0; j < 4; ++j) {
      a[j]     = (short)f2bf(v0[j]);
      a[4 + j] = (short)f2bf(v1[j]);
    }
    *(short8*)(xbr + kc * 32) = a;
    short8 b = *(const short8*)(sr + kc * 32);
    acc = __builtin_amdgcn_mfma_f32_16x16x32_bf16(a, b, acc, 0, 0, 0);
  }

  // D: lane(lr,lg) reg i = score[token=lg*4+i][tile=lr]. Top-2 reduce over tile axis (lr).
  float m1[4], m2v[4]; int i1[4];
#pragma unroll
  for (int i = 0; i < 4; ++i) { m1[i] = acc[i]; i1[i] = lr; m2v[i] = -1e30f; }
#pragma unroll
  for (int off = 1; off < 16; off <<= 1) {
#pragma unroll
    for (int i = 0; i < 4; ++i) {
      float bm  = __shfl_xor(m1[i], off);
      int   bi  = __shfl_xor(i1[i], off);
      float bm2 = __shfl_xor(m2v[i], off);
      bool bwin = (bm > m1[i]) || (bm == m1[i] && bi < i1[i]);
      float loser = bwin ? m1[i] : bm;
      m2v[i] = fmaxf(fmaxf(m2v[i], bm2), loser);
      if (bwin) { m1[i] = bm; i1[i] = bi; }
    }
  }
  if (lr == 0) {
#pragma unroll
    for (int i = 0; i < 4; ++i) {
      int tok = tok0 + lg * 4 + i;
      tidx[tok] = i1[i];
      oidx[tok] = (float)i1[i];
      if (m1[i] - m2v[i] < GAPTHR) {
        int p = atomicAdd(nfix, 1);
        fixlist[p] = tok;
      }
    }
  }
}

// ---- exact f64 rescore for close-call tokens (one wave per token) ----
__global__ __launch_bounds__(256) void k_fix(const float* __restrict__ x,
    const unsigned int* __restrict__ mask, const int* __restrict__ fixlist,
    const int* __restrict__ nfix, int* __restrict__ tidx, float* __restrict__ oidx)
{
  int n = *nfix;
  int l = threadIdx.x & 63;
  int gw = (blockIdx.x * 256 + threadIdx.x) >> 6;
  int nw = (gridDim.x * 256) >> 6;
  int t = l & 15, seg = l >> 4;

  for (int i = gw; i < n; i += nw) {
    int tok = fixlist[i];
    const float* xr = x + (size_t)tok * DM + seg * 256;
    const unsigned int* mr = mask + seg * 256;
    double acc0 = 0.0, acc1 = 0.0;
    for (int j = 0; j < 256; j += 4) {
      f32x4 xv = *(const f32x4*)(xr + j);
      u32x4 mv = *(const u32x4*)(mr + j);
#pragma unroll
      for (int u = 0; u < 4; ++u) {
        double c = ((mv[u] >> t) & 1u) ? (double)xv[u]
                 : (((mv[u] >> (16 + t)) & 1u) ? -(double)xv[u] : 0.0);
        if (u & 1) acc1 += c; else acc0 += c;
      }
    }
    double s = acc0 + acc1;
    s += __shfl_xor(s, 16);
    s += __shfl_xor(s, 32);      // lanes 0-15 now hold full tile sums (replicated)
    double bv = s; int bi = t;
#pragma unroll
    for (int off = 1; off < 16; off <<= 1) {
      double ov = __shfl_xor(bv, off);
      int   oi = __shfl_xor(bi, off);
      if (ov > bv || (ov == bv && oi < bi)) { bv = ov; bi = oi; }
    }
    if (l == 0) { tidx[tok] = bi; oidx[tok] = (float)bi; }
  }
}

// ---- histogram of final routing ----
__global__ __launch_bounds__(256) void k_count(const int* __restrict__ tidx, int* __restrict__ counts) {
  __shared__ int h[16];
  if (threadIdx.x < 16) h[threadIdx.x] = 0;
  __syncthreads();
  int i = blockIdx.x * 256 + threadIdx.x;
  atomicAdd(&h[tidx[i]], 1);
  __syncthreads();
  if (threadIdx.x < 16 && h[threadIdx.x]) atomicAdd(&counts[threadIdx.x], h[threadIdx.x]);
}

// ---- W f32 -> bf16 ----
__global__ __launch_bounds__(256) void k_wconv(const float* __restrict__ W, unsigned short* __restrict__ Wb) {
  const f32x4* W4 = (const f32x4*)W;
  u16x4* O = (u16x4*)Wb;
  int n4 = NT * NC * DM / 4;
  for (int i = blockIdx.x * blockDim.x + threadIdx.x; i < n4; i += gridDim.x * blockDim.x) {
    f32x4 v = W4[i];
    u16x4 o;
#pragma unroll
    for (int j = 0; j < 4; ++j) o[j] = f2bf(v[j]);
    O[i] = o;
  }
}

// ---- padded exclusive scan of counts (pad to 128) ----
__global__ void k_scan(const int* __restrict__ counts, int* __restrict__ offs) {
  if (threadIdx.x == 0) {
    int s = 0;
    for (int t = 0; t < NT; ++t) {
      offs[t] = s;
      s += (counts[t] + 127) & ~127;
    }
    offs[NT] = s;
  }
}

// ---- scatter tokens into per-tile segments ----
__global__ __launch_bounds__(256) void k_place(const int* __restrict__ tidx, const int* __restrict__ offs,
                                               int* __restrict__ cursor, int* __restrict__ perm) {
  int tok = blockIdx.x * 256 + threadIdx.x;
  if (tok >= B_TOK) return;
  int t = tidx[tok];
  int pos = atomicAdd(&cursor[t], 1);
  perm[offs[t] + pos] = tok;
}

// ---- grouped GEMM: 128x128 tile, BK=64, 4 waves, mfma 16x16x32 bf16 ----
__global__ __launch_bounds__(256) void k_gemm(const unsigned short* __restrict__ xb,
    const unsigned short* __restrict__ Wb, const float* __restrict__ bias,
    const int* __restrict__ perm, const int* __restrict__ offs, float* __restrict__ out)
{
  __shared__ unsigned short As[128 * 64];
  __shared__ unsigned short Bs[128 * 64];
  int bid0 = blockIdx.x;
  int bid = (bid0 & 7) * 528 + (bid0 >> 3);   // bijective XCD swizzle (4224 = 8*528)
  int mb = bid >> 3, nb = bid & 7;
  int total = offs[NT];
  int m0 = mb << 7;
  if (m0 >= total) return;
  int t = 0;
#pragma unroll
  for (int tt = 0; tt < NT; ++tt) if (m0 >= offs[tt + 1]) t = tt + 1;
  int c0 = nb << 7;
  int tid = threadIdx.x;

  int rowg = tid >> 3;
  int ks8 = (tid & 7) * 8;
  const unsigned short* gA[4];
  const unsigned short* gB[4];
  const unsigned short* gWt = Wb + (size_t)t * NC * DM;
#pragma unroll
  for (int r = 0; r < 4; ++r) {
    int row = r * 32 + rowg;
    int tk = perm[m0 + row]; if (tk < 0) tk = 0;
    gA[r] = xb + (size_t)tk * DM + ks8;
    gB[r] = gWt + (size_t)(c0 + row) * DM + ks8;
  }

  f32x4 acc[4][4];
#pragma unroll
  for (int m = 0; m < 4; ++m)
#pragma unroll
    for (int n = 0; n < 4; ++n) acc[m][n] = (f32x4){0.f, 0.f, 0.f, 0.f};

  int w = tid >> 6, l = tid & 63;
  int wr = w >> 1, wc = w & 1;
  int lr = l & 15, lk = l >> 4;

  for (int kk = 0; kk < DM; kk += 64) {
    __syncthreads();
#pragma unroll
    for (int r = 0; r < 4; ++r) {
      __builtin_amdgcn_global_load_lds(AS1(gA[r] + kk), AS3(As + (r * 256 + tid) * 8), 16, 0, 0);
      __builtin_amdgcn_global_load_lds(AS1(gB[r] + kk), AS3(Bs + (r * 256 + tid) * 8), 16, 0, 0);
    }
    __syncthreads();
#pragma unroll
    for (int ks = 0; ks < 2; ++ks) {
      short8 a[4], b[4];
#pragma unroll
      for (int m = 0; m < 4; ++m)
        a[m] = *(const short8*)&As[(wr * 64 + m * 16 + lr) * 64 + ks * 32 + lk * 8];
#pragma unroll
      for (int n = 0; n < 4; ++n)
        b[n] = *(const short8*)&Bs[(wc * 64 + n * 16 + lr) * 64 + ks * 32 + lk * 8];
#pragma unroll
      for (int m = 0; m < 4; ++m)
#pragma unroll
        for (int n = 0; n < 4; ++n)
          acc[m][n] = __builtin_amdgcn_mfma_f32_16x16x32_bf16(a[m], b[n], acc[m][n], 0, 0, 0);
    }
  }

  float bv[4];
#pragma unroll
  for (int n = 0; n < 4; ++n) bv[n] = bias[t * NC + c0 + wc * 64 + n * 16 + lr];
#pragma unroll
  for (int m = 0; m < 4; ++m) {
#pragma unroll
    for (int j = 0; j < 4; ++j) {
      int prow = m0 + wr * 64 + m * 16 + lk * 4 + j;
      int tok = perm[prow];
      if (tok >= 0) {
#pragma unroll
        for (int n = 0; n < 4; ++n)
          out[(size_t)tok * NC + c0 + wc * 64 + n * 16 + lr] = acc[m][n][j] + bv[n];
      }
    }
  }
}

extern "C" void kernel_launch(void* const* d_in, const int* in_sizes, int n_in,
                              void* d_out, int out_size, void* d_ws, size_t ws_size,
                              hipStream_t stream) {
  const float* x    = (const float*)d_in[0];
  const float* sigs = (const float*)d_in[1];
  const float* W    = (const float*)d_in[2];
  const float* bias = (const float*)d_in[3];
  float* out = (float*)d_out;
  float* oidx = out + (size_t)B_TOK * NC;

  char* ws = (char*)d_ws;
  unsigned short* xb   = (unsigned short*)ws;                    // 134217728 B
  unsigned short* Wb   = (unsigned short*)(ws + 134217728);      // 33554432 B
  int* perm            = (int*)(ws + 167772160);                 // 270336 B (67584 rows)
  int* tidx            = (int*)(ws + 168042496);                 // 262144 B
  unsigned int* mask   = (unsigned int*)(ws + 168304640);        // 4096 B
  unsigned short* Sb   = (unsigned short*)(ws + 168308736);      // 32768 B
  int* fixlist         = (int*)(ws + 168341504);                 // 262144 B
  int* ctrl            = (int*)(ws + 168603648);                 // counts16 cursor16 offs17 nfix1
  int* counts = ctrl;
  int* cursor = ctrl + 16;
  int* offs   = ctrl + 32;
  int* nfix   = ctrl + 49;

  hipMemsetAsync(perm, 0xFF, 270336, stream);   // perm = -1 (pad marker)
  hipMemsetAsync(ctrl, 0, 256, stream);

  k_prep<<<1, 1024, 0, stream>>>(sigs, mask, Sb);
  k_scores<<<1024, 256, 0, stream>>>(x, Sb, xb, tidx, oidx, fixlist, nfix);
  k_fix<<<512, 256, 0, stream>>>(x, mask, fixlist, nfix, tidx, oidx);
  k_count<<<256, 256, 0, stream>>>(tidx, counts);
  k_scan<<<1, 64, 0, stream>>>(counts, offs);
  k_place<<<256, 256, 0, stream>>>(tidx, offs, cursor, perm);
  k_wconv<<<2048, 256, 0, stream>>>(W, Wb);
  k_gemm<<<dim3(528 * 8), 256, 0, stream>>>(xb, Wb, bias, perm, offs, out);
}

// Round 4
// 646.566 us; speedup vs baseline: 2.0188x; 1.0326x over previous
//
#include <hip/hip_runtime.h>
#include <hip/hip_bf16.h>
#include <stdint.h>

#define B_TOK 65536
#define DM 1024
#define NC 1024
#define NT 16
#define GAPTHR 0.25f

typedef __attribute__((ext_vector_type(4))) float f32x4;
typedef __attribute__((ext_vector_type(4))) unsigned int u32x4;
typedef __attribute__((ext_vector_type(4))) unsigned short u16x4;
typedef __attribute__((ext_vector_type(8))) short short8;

#define AS1(p) ((__attribute__((address_space(1))) void*)(p))
#define AS3(p) ((__attribute__((address_space(3))) void*)(p))

static __device__ inline unsigned short f2bf(float f) {
  __hip_bfloat16 h = __float2bfloat16(f);
  unsigned short u;
  __builtin_memcpy(&u, &h, 2);
  return u;
}

// ---- prep: ternary masks (bit t = pos, bit 16+t = neg) + ternary bf16 matrix S[16][1024] ----
__global__ void k_prep(const float* __restrict__ sigs, unsigned int* __restrict__ mask,
                       unsigned short* __restrict__ Sb) {
  int d = threadIdx.x;
  unsigned int m = 0;
#pragma unroll
  for (int t = 0; t < NT; ++t) {
    float s = sigs[t * DM + d];
    float q = (s > 0.3f) ? 1.0f : ((s < -0.3f) ? -1.0f : 0.0f);
    if (s > 0.3f) m |= 1u << t;
    else if (s < -0.3f) m |= 1u << (16 + t);
    Sb[t * DM + d] = f2bf(q);   // {-1,0,1} exact in bf16
  }
  mask[d] = m;
}

// ---- provisional scores via bf16 MFMA + top-2 gap + x->bf16 ----
__global__ __launch_bounds__(256) void k_scores(const float* __restrict__ x,
    const unsigned short* __restrict__ Sb, unsigned short* __restrict__ xb,
    int* __restrict__ tidx, float* __restrict__ oidx,
    int* __restrict__ fixlist, int* __restrict__ nfix)
{
  int tid = threadIdx.x;
  int w = tid >> 6, l = tid & 63;
  int lr = l & 15, lg = l >> 4;
  int tok0 = blockIdx.x * 64 + w * 16;

  const float* xr = x + (size_t)(tok0 + lr) * DM + lg * 8;
  unsigned short* xbr = xb + (size_t)(tok0 + lr) * DM + lg * 8;
  const unsigned short* sr = Sb + (size_t)lr * DM + lg * 8;

  f32x4 acc = (f32x4){0.f, 0.f, 0.f, 0.f};
  for (int kc = 0; kc < 32; ++kc) {
    f32x4 v0 = *(const f32x4*)(xr + kc * 32);
    f32x4 v1 = *(const f32x4*)(xr + kc * 32 + 4);
    short8 a;
#pragma unroll
    for (int j = 0; j < 4; ++j) {
      a[j]     = (short)f2bf(v0[j]);
      a[4 + j] = (short)f2bf(v1[j]);
    }
    *(short8*)(xbr + kc * 32) = a;
    short8 b = *(const short8*)(sr + kc * 32);
    acc = __builtin_amdgcn_mfma_f32_16x16x32_bf16(a, b, acc, 0, 0, 0);
  }

  // D: lane(lr,lg) reg i = score[token=lg*4+i][tile=lr]. Top-2 reduce over tile axis (lr).
  float m1[4], m2v[4]; int i1[4];
#pragma unroll
  for (int i = 0; i < 4; ++i) { m1[i] = acc[i]; i1[i] = lr; m2v[i] = -1e30f; }
#pragma unroll
  for (int off = 1; off < 16; off <<= 1) {
#pragma unroll
    for (int i = 0; i < 4; ++i) {
      float bm  = __shfl_xor(m1[i], off);
      int   bi  = __shfl_xor(i1[i], off);
      float bm2 = __shfl_xor(m2v[i], off);
      bool bwin = (bm > m1[i]) || (bm == m1[i] && bi < i1[i]);
      float loser = bwin ? m1[i] : bm;
      m2v[i] = fmaxf(fmaxf(m2v[i], bm2), loser);
      if (bwin) { m1[i] = bm; i1[i] = bi; }
    }
  }
  if (lr == 0) {
#pragma unroll
    for (int i = 0; i < 4; ++i) {
      int tok = tok0 + lg * 4 + i;
      tidx[tok] = i1[i];
      oidx[tok] = (float)i1[i];
      if (m1[i] - m2v[i] < GAPTHR) {
        int p = atomicAdd(nfix, 1);
        fixlist[p] = tok;
      }
    }
  }
}

// ---- exact f64 rescore for close-call tokens (one wave per token) ----
__global__ __launch_bounds__(256) void k_fix(const float* __restrict__ x,
    const unsigned int* __restrict__ mask, const int* __restrict__ fixlist,
    const int* __restrict__ nfix, int* __restrict__ tidx, float* __restrict__ oidx)
{
  int n = *nfix;
  int l = threadIdx.x & 63;
  int gw = (blockIdx.x * 256 + threadIdx.x) >> 6;
  int nw = (gridDim.x * 256) >> 6;
  int t = l & 15, seg = l >> 4;

  for (int i = gw; i < n; i += nw) {
    int tok = fixlist[i];
    const float* xr = x + (size_t)tok * DM + seg * 256;
    const unsigned int* mr = mask + seg * 256;
    double acc0 = 0.0, acc1 = 0.0;
    for (int j = 0; j < 256; j += 4) {
      f32x4 xv = *(const f32x4*)(xr + j);
      u32x4 mv = *(const u32x4*)(mr + j);
#pragma unroll
      for (int u = 0; u < 4; ++u) {
        double c = ((mv[u] >> t) & 1u) ? (double)xv[u]
                 : (((mv[u] >> (16 + t)) & 1u) ? -(double)xv[u] : 0.0);
        if (u & 1) acc1 += c; else acc0 += c;
      }
    }
    double s = acc0 + acc1;
    s += __shfl_xor(s, 16);
    s += __shfl_xor(s, 32);
    double bv = s; int bi = t;
#pragma unroll
    for (int off = 1; off < 16; off <<= 1) {
      double ov = __shfl_xor(bv, off);
      int   oi = __shfl_xor(bi, off);
      if (ov > bv || (ov == bv && oi < bi)) { bv = ov; bi = oi; }
    }
    if (l == 0) { tidx[tok] = bi; oidx[tok] = (float)bi; }
  }
}

// ---- histogram of final routing ----
__global__ __launch_bounds__(256) void k_count(const int* __restrict__ tidx, int* __restrict__ counts) {
  __shared__ int h[16];
  if (threadIdx.x < 16) h[threadIdx.x] = 0;
  __syncthreads();
  int i = blockIdx.x * 256 + threadIdx.x;
  atomicAdd(&h[tidx[i]], 1);
  __syncthreads();
  if (threadIdx.x < 16 && h[threadIdx.x]) atomicAdd(&counts[threadIdx.x], h[threadIdx.x]);
}

// ---- W f32 -> bf16 ----
__global__ __launch_bounds__(256) void k_wconv(const float* __restrict__ W, unsigned short* __restrict__ Wb) {
  const f32x4* W4 = (const f32x4*)W;
  u16x4* O = (u16x4*)Wb;
  int n4 = NT * NC * DM / 4;
  for (int i = blockIdx.x * blockDim.x + threadIdx.x; i < n4; i += gridDim.x * blockDim.x) {
    f32x4 v = W4[i];
    u16x4 o;
#pragma unroll
    for (int j = 0; j < 4; ++j) o[j] = f2bf(v[j]);
    O[i] = o;
  }
}

// ---- padded exclusive scan of counts (pad to 128) ----
__global__ void k_scan(const int* __restrict__ counts, int* __restrict__ offs) {
  if (threadIdx.x == 0) {
    int s = 0;
    for (int t = 0; t < NT; ++t) {
      offs[t] = s;
      s += (counts[t] + 127) & ~127;
    }
    offs[NT] = s;
  }
}

// ---- scatter tokens into per-tile segments ----
__global__ __launch_bounds__(256) void k_place(const int* __restrict__ tidx, const int* __restrict__ offs,
                                               int* __restrict__ cursor, int* __restrict__ perm) {
  int tok = blockIdx.x * 256 + threadIdx.x;
  if (tok >= B_TOK) return;
  int t = tidx[tok];
  int pos = atomicAdd(&cursor[t], 1);
  perm[offs[t] + pos] = tok;
}

// ---- grouped GEMM: 128x128 tile, BK=64, mfma 16x16x32 bf16, XOR-swizzled LDS (T2) ----
// LDS logical [row][k]: physical 16B-slot s of row r holds logical k-chunk (s ^ (r&7)).
// Staging: linear LDS dest + pre-swizzled GLOBAL source (rule: both-sides-or-neither).
__global__ __launch_bounds__(256) void k_gemm(const unsigned short* __restrict__ xb,
    const unsigned short* __restrict__ Wb, const float* __restrict__ bias,
    const int* __restrict__ perm, const int* __restrict__ offs, float* __restrict__ out)
{
  __shared__ unsigned short As[128 * 64];
  __shared__ unsigned short Bs[128 * 64];
  int bid0 = blockIdx.x;
  int bid = (bid0 & 7) * 528 + (bid0 >> 3);   // bijective XCD swizzle (4224 = 8*528)
  int mb = bid >> 3, nb = bid & 7;
  int total = offs[NT];
  int m0 = mb << 7;
  if (m0 >= total) return;
  int t = 0;
#pragma unroll
  for (int tt = 0; tt < NT; ++tt) if (m0 >= offs[tt + 1]) t = tt + 1;
  int c0 = nb << 7;
  int tid = threadIdx.x;

  int rowg = tid >> 3;                                   // 0..31
  int ks8 = (((tid & 7) ^ (rowg & 7)) << 3);             // swizzled global k-offset (elements)
  const unsigned short* gA[4];
  const unsigned short* gB[4];
  const unsigned short* gWt = Wb + (size_t)t * NC * DM;
#pragma unroll
  for (int r = 0; r < 4; ++r) {
    int row = r * 32 + rowg;                             // row&7 == rowg&7
    int tk = perm[m0 + row]; if (tk < 0) tk = 0;
    gA[r] = xb + (size_t)tk * DM + ks8;
    gB[r] = gWt + (size_t)(c0 + row) * DM + ks8;
  }

  f32x4 acc[4][4];
#pragma unroll
  for (int m = 0; m < 4; ++m)
#pragma unroll
    for (int n = 0; n < 4; ++n) acc[m][n] = (f32x4){0.f, 0.f, 0.f, 0.f};

  int w = tid >> 6, l = tid & 63;
  int wr = w >> 1, wc = w & 1;
  int lr = l & 15, lk = l >> 4;
  int sx = lr & 7;                                       // row&7 on the read side

  for (int kk = 0; kk < DM; kk += 64) {
    __syncthreads();
#pragma unroll
    for (int r = 0; r < 4; ++r) {
      __builtin_amdgcn_global_load_lds(AS1(gA[r] + kk), AS3(As + (r * 256 + tid) * 8), 16, 0, 0);
      __builtin_amdgcn_global_load_lds(AS1(gB[r] + kk), AS3(Bs + (r * 256 + tid) * 8), 16, 0, 0);
    }
    __syncthreads();
#pragma unroll
    for (int ks = 0; ks < 2; ++ks) {
      short8 a[4], b[4];
#pragma unroll
      for (int m = 0; m < 4; ++m)
        a[m] = *(const short8*)&As[(wr * 64 + m * 16 + lr) * 64 + (((ks * 4 + lk) ^ sx) << 3)];
#pragma unroll
      for (int n = 0; n < 4; ++n)
        b[n] = *(const short8*)&Bs[(wc * 64 + n * 16 + lr) * 64 + (((ks * 4 + lk) ^ sx) << 3)];
#pragma unroll
      for (int m = 0; m < 4; ++m)
#pragma unroll
        for (int n = 0; n < 4; ++n)
          acc[m][n] = __builtin_amdgcn_mfma_f32_16x16x32_bf16(a[m], b[n], acc[m][n], 0, 0, 0);
    }
  }

  float bv[4];
#pragma unroll
  for (int n = 0; n < 4; ++n) bv[n] = bias[t * NC + c0 + wc * 64 + n * 16 + lr];
#pragma unroll
  for (int m = 0; m < 4; ++m) {
#pragma unroll
    for (int j = 0; j < 4; ++j) {
      int prow = m0 + wr * 64 + m * 16 + lk * 4 + j;
      int tok = perm[prow];
      if (tok >= 0) {
#pragma unroll
        for (int n = 0; n < 4; ++n)
          out[(size_t)tok * NC + c0 + wc * 64 + n * 16 + lr] = acc[m][n][j] + bv[n];
      }
    }
  }
}

extern "C" void kernel_launch(void* const* d_in, const int* in_sizes, int n_in,
                              void* d_out, int out_size, void* d_ws, size_t ws_size,
                              hipStream_t stream) {
  const float* x    = (const float*)d_in[0];
  const float* sigs = (const float*)d_in[1];
  const float* W    = (const float*)d_in[2];
  const float* bias = (const float*)d_in[3];
  float* out = (float*)d_out;
  float* oidx = out + (size_t)B_TOK * NC;

  char* ws = (char*)d_ws;
  unsigned short* xb   = (unsigned short*)ws;                    // 134217728 B
  unsigned short* Wb   = (unsigned short*)(ws + 134217728);      // 33554432 B
  int* perm            = (int*)(ws + 167772160);                 // 270336 B (67584 rows)
  int* tidx            = (int*)(ws + 168042496);                 // 262144 B
  unsigned int* mask   = (unsigned int*)(ws + 168304640);        // 4096 B
  unsigned short* Sb   = (unsigned short*)(ws + 168308736);      // 32768 B
  int* fixlist         = (int*)(ws + 168341504);                 // 262144 B
  int* ctrl            = (int*)(ws + 168603648);                 // counts16 cursor16 offs17 nfix1
  int* counts = ctrl;
  int* cursor = ctrl + 16;
  int* offs   = ctrl + 32;
  int* nfix   = ctrl + 49;

  hipMemsetAsync(perm, 0xFF, 270336, stream);   // perm = -1 (pad marker)
  hipMemsetAsync(ctrl, 0, 256, stream);

  k_prep<<<1, 1024, 0, stream>>>(sigs, mask, Sb);
  k_scores<<<1024, 256, 0, stream>>>(x, Sb, xb, tidx, oidx, fixlist, nfix);
  k_fix<<<512, 256, 0, stream>>>(x, mask, fixlist, nfix, tidx, oidx);
  k_count<<<256, 256, 0, stream>>>(tidx, counts);
  k_scan<<<1, 64, 0, stream>>>(counts, offs);
  k_place<<<256, 256, 0, stream>>>(tidx, offs, cursor, perm);
  k_wconv<<<2048, 256, 0, stream>>>(W, Wb);
  k_gemm<<<dim3(528 * 8), 256, 0, stream>>>(xb, Wb, bias, perm, offs, out);
}